// Round 4
// baseline (393.726 us; speedup 1.0000x reference)
//
#include <hip/hip_runtime.h>
#include <hip/hip_fp16.h>
#include <stddef.h>

// Problem: N=4, S=4096, E=1024, H=16, D=64. fp32 in/out.
// Reference = "attention over heads": per (n,s) position, 16x16 softmax across
// heads, then scrambled (N,H,S,D)->(N,S,E) reshape + output projection.
// Pipeline (f16 MFMA compute, fp32 accumulate; absmax ~8e-3 << 4.09e-2):
//   K0: convert x, Wq..Wo fp32 -> f16 in ws
//   K1: QKV projections (3x GEMM 16384x1024x1024 NT +bias) -> ws f16
//   K2: per-position head-attention; writes Ab in SCRAMBLED layout (coalesced
//       128B segments) so K3 is a plain GEMM
//   K3: output projection (plain NT GEMM) -> fp32 out
// GEMMs: 128x128 tile, BK=32, mfma_f32_32x32x16_f16 (2x2 waves x 2x2 frags),
// global_load_lds width-16 staging with XOR granule swizzle (g^=row&3) so the
// 32-row fragment reads cover all 32 LDS banks.

typedef _Float16 f16_t;
typedef _Float16 f16x8 __attribute__((ext_vector_type(8)));
typedef _Float16 f16x4 __attribute__((ext_vector_type(4)));
typedef float    f32x4  __attribute__((ext_vector_type(4)));
typedef float    f32x16 __attribute__((ext_vector_type(16)));

static constexpr int Sdim = 4096;
static constexpr int Edim = 1024;
static constexpr int Mrows = 4 * Sdim;                  // 16384
static constexpr size_t MATEL = (size_t)Mrows * Edim;   // 16.7M
static constexpr size_t WEL = (size_t)Edim * Edim;      // 1.05M
static constexpr int BM = 128, BN = 128, BK = 32;
static constexpr int TILE = BM * BK;                    // 4096 f16 = 8KB

__device__ __forceinline__ void gload_lds16(const f16_t* g, f16_t* l) {
  // async global->LDS, 16B/lane; LDS dest = wave-uniform base + lane*16 (m97)
  __builtin_amdgcn_global_load_lds(
      (const __attribute__((address_space(1))) void*)g,
      (__attribute__((address_space(3))) void*)l, 16, 0, 0);
}

// ---------------- fp32 -> f16 convert ----------------
__global__ __launch_bounds__(256) void cvt_kernel(
    const float* __restrict__ s0, const float* __restrict__ s1,
    const float* __restrict__ s2, const float* __restrict__ s3,
    const float* __restrict__ s4,
    f16_t* __restrict__ d0, f16_t* __restrict__ d1, f16_t* __restrict__ d2,
    f16_t* __restrict__ d3, f16_t* __restrict__ d4) {
  const float* s; f16_t* d; size_t nv;  // nv = count of float4 groups
  switch (blockIdx.y) {
    case 0: s = s0; d = d0; nv = MATEL / 4; break;
    case 1: s = s1; d = d1; nv = WEL / 4; break;
    case 2: s = s2; d = d2; nv = WEL / 4; break;
    case 3: s = s3; d = d3; nv = WEL / 4; break;
    default: s = s4; d = d4; nv = WEL / 4; break;
  }
  const size_t stride = (size_t)gridDim.x * 256;
  for (size_t i = blockIdx.x * 256 + threadIdx.x; i < nv; i += stride) {
    const f32x4 v = ((const f32x4*)s)[i];
    f16x4 h;
#pragma unroll
    for (int j = 0; j < 4; j++) h[j] = (f16_t)v[j];
    ((f16x4*)d)[i] = h;
  }
}

// ---------------- GEMM core (32x32x16 f16 MFMA, NT, +fp32 bias) ----------------
// C[m,n] = sum_k A[m,k]*B[n,k] + bias[n].
// LDS layout: granule (16B) at (row, g') holds global k-granule g = g'^(row&3).
template <typename TOut>
__device__ __forceinline__ void gemm_f16(const f16_t* __restrict__ A,
                                         const f16_t* __restrict__ B,
                                         const float* __restrict__ bias,
                                         TOut* __restrict__ C) {
  __shared__ __align__(16) f16_t As[TILE];
  __shared__ __align__(16) f16_t Bs[TILE];
  const int t = threadIdx.x;
  const int bm = blockIdx.x * BM;
  const int bn = blockIdx.y * BN;
  const int lane = t & 63;
  const int wave = t >> 6;
  const int wm = (wave >> 1) * 64;  // 2x2 waves of 64x64
  const int wn = (wave & 1) * 64;
  const int r32 = lane & 31;
  const int kgrp = lane >> 5;

  f32x16 acc[2][2] = {};

  // staging: thread t fills LDS granule t (As + t*16B) == (row t>>2, g'=t&3);
  // swizzle: fetch global granule g = (t&3) ^ (row&3)
  const int lr = t >> 2;
  const int lc = ((t & 3) ^ (lr & 3)) * 8;
  f16_t* la = &As[t * 8];
  f16_t* lb = &Bs[t * 8];
  const f16_t* gaBase = A + (size_t)(bm + lr) * Edim + lc;
  const f16_t* gbBase = B + (size_t)(bn + lr) * Edim + lc;

  for (int k0 = 0; k0 < Edim; k0 += BK) {
    gload_lds16(gaBase + k0, la);
    gload_lds16(gaBase + k0 + (size_t)64 * Edim, la + 64 * BK);
    gload_lds16(gbBase + k0, lb);
    gload_lds16(gbBase + k0 + (size_t)64 * Edim, lb + 64 * BK);
    __syncthreads();  // drains vmcnt before barrier

#pragma unroll
    for (int ks = 0; ks < 2; ks++) {  // two K=16 steps per BK=32 tile
      const int gidx = ((ks * 2 + kgrp) ^ (r32 & 3)) * 8;  // swizzled granule
      f16x8 af[2], bf[2];
#pragma unroll
      for (int i = 0; i < 2; i++)
        af[i] = *(const f16x8*)&As[(wm + i * 32 + r32) * BK + gidx];
#pragma unroll
      for (int j = 0; j < 2; j++)
        bf[j] = *(const f16x8*)&Bs[(wn + j * 32 + r32) * BK + gidx];
#pragma unroll
      for (int i = 0; i < 2; i++)
#pragma unroll
        for (int j = 0; j < 2; j++)
          acc[i][j] = __builtin_amdgcn_mfma_f32_32x32x16_f16(af[i], bf[j], acc[i][j], 0, 0, 0);
    }
    __syncthreads();
  }

  // Epilogue. 32x32 C/D: col = lane&31, row = (reg&3) + 8*(reg>>2) + 4*(lane>>5)
  // [m74/m101-verified]
#pragma unroll
  for (int j = 0; j < 2; j++) {
    const int col = bn + wn + j * 32 + r32;
    const float bv = bias[col];
#pragma unroll
    for (int i = 0; i < 2; i++) {
      const int rb = bm + wm + i * 32 + 4 * kgrp;
#pragma unroll
      for (int reg = 0; reg < 16; reg++) {
        const int row = rb + (reg & 3) + 8 * (reg >> 2);
        C[(size_t)row * Edim + col] = (TOut)(acc[i][j][reg] + bv);
      }
    }
  }
}

__global__ __launch_bounds__(256) void qkv_kernel(
    const f16_t* __restrict__ x,
    const f16_t* __restrict__ Wq, const float* __restrict__ bq,
    const f16_t* __restrict__ Wk, const float* __restrict__ bk,
    const f16_t* __restrict__ Wv, const float* __restrict__ bv,
    f16_t* __restrict__ Qb, f16_t* __restrict__ Kb, f16_t* __restrict__ Vb) {
  const f16_t* W; const float* bi; f16_t* C;
  if (blockIdx.z == 0)      { W = Wq; bi = bq; C = Qb; }
  else if (blockIdx.z == 1) { W = Wk; bi = bk; C = Kb; }
  else                      { W = Wv; bi = bv; C = Vb; }
  gemm_f16<f16_t>(x, W, bi, C);
}

__global__ __launch_bounds__(256) void outp_kernel(
    const f16_t* __restrict__ Ab, const f16_t* __restrict__ Wo,
    const float* __restrict__ bo, float* __restrict__ out) {
  gemm_f16<float>(Ab, Wo, bo, out);
}

// ---------------- per-position head-attention ----------------
// One 256-thread block per (n,s) position. Padded LDS -> conflict-free.
// Writes Ab in SCRAMBLED layout: (n,h,s,d) -> row n*4096 + h*256 + s/16,
// col (s%16)*64 + d. Per-wave: 4 rows x 128B contiguous -> coalesced.
__global__ __launch_bounds__(256) void attn_kernel(const f16_t* __restrict__ Qb,
                                                   const f16_t* __restrict__ Kb,
                                                   const f16_t* __restrict__ Vb,
                                                   f16_t* __restrict__ Ab) {
  const int pos = blockIdx.x;  // n*S + s
  __shared__ float q[16][65], k[16][65], v[16][65];
  __shared__ float p[16][17];
  const int t = threadIdx.x;
  const f16_t* Qr = Qb + (size_t)pos * Edim;
  const f16_t* Kr = Kb + (size_t)pos * Edim;
  const f16_t* Vr = Vb + (size_t)pos * Edim;

  {  // load 4 halves per array per thread (8B, coalesced)
    const int h = t >> 4, d0 = (t & 15) * 4;  // h*64+d0 == 4t
    const f16x4 qq = *(const f16x4*)(Qr + 4 * t);
    const f16x4 kk = *(const f16x4*)(Kr + 4 * t);
    const f16x4 vv = *(const f16x4*)(Vr + 4 * t);
#pragma unroll
    for (int j = 0; j < 4; j++) {
      q[h][d0 + j] = (float)qq[j];
      k[h][d0 + j] = (float)kk[j];
      v[h][d0 + j] = (float)vv[j];
    }
  }
  __syncthreads();
  {  // 16x16 scores: thread t -> (qh, kh)
    const int qh = t >> 4, kh = t & 15;
    float a = 0.f;
#pragma unroll
    for (int d = 0; d < 64; d++) a += q[qh][d] * k[kh][d];
    p[qh][kh] = a * 0.125f;  // 1/sqrt(64)
  }
  __syncthreads();
  if (t < 16) {  // softmax over kh for row t
    float m = -1e30f;
#pragma unroll
    for (int kh = 0; kh < 16; kh++) m = fmaxf(m, p[t][kh]);
    float e[16], sum = 0.f;
#pragma unroll
    for (int kh = 0; kh < 16; kh++) { e[kh] = __expf(p[t][kh] - m); sum += e[kh]; }
    const float inv = 1.f / sum;
#pragma unroll
    for (int kh = 0; kh < 16; kh++) p[t][kh] = e[kh] * inv;
  }
  __syncthreads();
  {  // mix: 4 outputs per thread, scrambled store
    const int h = t >> 4, d0 = (t & 15) * 4;
    float o0 = 0.f, o1 = 0.f, o2 = 0.f, o3 = 0.f;
#pragma unroll
    for (int l = 0; l < 16; l++) {
      const float w = p[h][l];
      o0 += w * v[l][d0];
      o1 += w * v[l][d0 + 1];
      o2 += w * v[l][d0 + 2];
      o3 += w * v[l][d0 + 3];
    }
    f16x4 r;
    r[0] = (f16_t)o0; r[1] = (f16_t)o1; r[2] = (f16_t)o2; r[3] = (f16_t)o3;
    const int srow = ((pos >> 12) << 12) + (h << 8) + ((pos & 4095) >> 4);
    const int scol = ((pos & 15) << 6) + d0;
    *(f16x4*)(Ab + (size_t)srow * Edim + scol) = r;
  }
}

// ---------------- launcher ----------------
extern "C" void kernel_launch(void* const* d_in, const int* in_sizes, int n_in,
                              void* d_out, int out_size, void* d_ws, size_t ws_size,
                              hipStream_t stream) {
  const float* x  = (const float*)d_in[0];
  const float* Wq = (const float*)d_in[1];
  const float* bq = (const float*)d_in[2];
  const float* Wk = (const float*)d_in[3];
  const float* bk = (const float*)d_in[4];
  const float* Wv = (const float*)d_in[5];
  const float* bv = (const float*)d_in[6];
  const float* Wo = (const float*)d_in[7];
  const float* bo = (const float*)d_in[8];
  float* out = (float*)d_out;

  f16_t* xh  = (f16_t*)d_ws;          // 33.5 MB
  f16_t* Wqh = xh + MATEL;            // 2 MB each
  f16_t* Wkh = Wqh + WEL;
  f16_t* Wvh = Wkh + WEL;
  f16_t* Woh = Wvh + WEL;
  f16_t* Qb  = Woh + WEL;             // 33.5 MB each
  f16_t* Kb  = Qb + MATEL;
  f16_t* Vb  = Kb + MATEL;
  f16_t* Ab  = Vb + MATEL;            // total ~176 MB (round-2 used ~201 MB OK)

  const dim3 blk(256);
  cvt_kernel<<<dim3(2048, 5), blk, 0, stream>>>(x, Wq, Wk, Wv, Wo,
                                                xh, Wqh, Wkh, Wvh, Woh);
  qkv_kernel<<<dim3(Mrows / BM, Edim / BN, 3), blk, 0, stream>>>(
      xh, Wqh, bq, Wkh, bk, Wvh, bv, Qb, Kb, Vb);
  attn_kernel<<<dim3(Mrows), blk, 0, stream>>>(Qb, Kb, Vb, Ab);
  outp_kernel<<<dim3(Mrows / BM, Edim / BN), blk, 0, stream>>>(Ab, Woh, bo, out);
}

// Round 5
// 348.239 us; speedup vs baseline: 1.1306x; 1.1306x over previous
//
#include <hip/hip_runtime.h>
#include <hip/hip_fp16.h>
#include <stddef.h>

// Problem: N=4, S=4096, E=1024, H=16, D=64. fp32 in/out.
// Reference = "attention over heads": per (n,s) position, 16x16 softmax across
// heads, then scrambled (N,H,S,D)->(N,S,E) reshape + output projection.
// Pipeline (f16 MFMA compute, fp32 accumulate; absmax ~8e-3 << 4.09e-2):
//   K0: convert x, Wq..Wo fp32 -> f16 in ws
//   K1: QKV projections (3x GEMM 16384x1024x1024 NT +bias) -> ws f16
//   K2: per-position head-attention, ONE WAVE per position, fully MFMA:
//       S^T = mfma_16x16x32(A=K, B=Q) -> P lands in A-frag layout for the
//       legacy mfma_16x16x16f16 PV product (no transpose); V via LDS.
//       Writes Ab in SCRAMBLED layout so K3 is a plain GEMM.
//   K3: output projection (plain NT GEMM, round-3 core) -> fp32 out
// GEMM core: 128x128 tile, BK=32, mfma_f32_16x16x32_f16, global_load_lds
// width-16 (m97 structure; benched 138us for the triple-GEMM dispatch).

typedef _Float16 f16_t;
typedef _Float16 f16x8 __attribute__((ext_vector_type(8)));
typedef _Float16 f16x4 __attribute__((ext_vector_type(4)));
typedef float    f32x4 __attribute__((ext_vector_type(4)));

static constexpr int Sdim = 4096;
static constexpr int Edim = 1024;
static constexpr int Mrows = 4 * Sdim;                  // 16384
static constexpr size_t MATEL = (size_t)Mrows * Edim;   // 16.7M
static constexpr size_t WEL = (size_t)Edim * Edim;      // 1.05M
static constexpr int BM = 128, BN = 128, BK = 32;
static constexpr int TILE = BM * BK;                    // 4096 f16 = 8KB

__device__ __forceinline__ void gload_lds16(const f16_t* g, f16_t* l) {
  // async global->LDS, 16B/lane; LDS dest = wave-uniform base + lane*16 (m97)
  __builtin_amdgcn_global_load_lds(
      (const __attribute__((address_space(1))) void*)g,
      (__attribute__((address_space(3))) void*)l, 16, 0, 0);
}

// ---------------- fp32 -> f16 convert ----------------
__global__ __launch_bounds__(256) void cvt_kernel(
    const float* __restrict__ s0, const float* __restrict__ s1,
    const float* __restrict__ s2, const float* __restrict__ s3,
    const float* __restrict__ s4,
    f16_t* __restrict__ d0, f16_t* __restrict__ d1, f16_t* __restrict__ d2,
    f16_t* __restrict__ d3, f16_t* __restrict__ d4) {
  const float* s; f16_t* d; size_t nv;  // nv = count of float4 groups
  switch (blockIdx.y) {
    case 0: s = s0; d = d0; nv = MATEL / 4; break;
    case 1: s = s1; d = d1; nv = WEL / 4; break;
    case 2: s = s2; d = d2; nv = WEL / 4; break;
    case 3: s = s3; d = d3; nv = WEL / 4; break;
    default: s = s4; d = d4; nv = WEL / 4; break;
  }
  const size_t stride = (size_t)gridDim.x * 256;
  for (size_t i = blockIdx.x * 256 + threadIdx.x; i < nv; i += stride) {
    const f32x4 v = ((const f32x4*)s)[i];
    f16x4 h;
#pragma unroll
    for (int j = 0; j < 4; j++) h[j] = (f16_t)v[j];
    ((f16x4*)d)[i] = h;
  }
}

// ---------------- GEMM core (16x16x32 f16 MFMA, NT, +fp32 bias) ----------------
// Round-3 structure (benched: 46us/GEMM). C[m,n] = sum_k A[m,k]*B[n,k] + bias[n].
template <typename TOut>
__device__ __forceinline__ void gemm_f16(const f16_t* __restrict__ A,
                                         const f16_t* __restrict__ B,
                                         const float* __restrict__ bias,
                                         TOut* __restrict__ C) {
  __shared__ __align__(16) f16_t As[TILE];
  __shared__ __align__(16) f16_t Bs[TILE];
  const int t = threadIdx.x;
  const int bm = blockIdx.x * BM;
  const int bn = blockIdx.y * BN;
  const int lane = t & 63;
  const int wave = t >> 6;
  const int wm = (wave >> 1) * 64;  // 2x2 waves of 64x64
  const int wn = (wave & 1) * 64;
  const int row16 = lane & 15;
  const int quad = lane >> 4;

  f32x4 acc[4][4] = {};

  // staging: thread t covers LDS f16[t*8 .. t*8+8) == row t>>2, col (t&3)*8
  const int lr = t >> 2;
  const int lc = (t & 3) * 8;
  f16_t* la = &As[t * 8];
  f16_t* lb = &Bs[t * 8];
  const f16_t* gaBase = A + (size_t)(bm + lr) * Edim + lc;
  const f16_t* gbBase = B + (size_t)(bn + lr) * Edim + lc;

  for (int k0 = 0; k0 < Edim; k0 += BK) {
    gload_lds16(gaBase + k0, la);
    gload_lds16(gaBase + k0 + (size_t)64 * Edim, la + 64 * BK);
    gload_lds16(gbBase + k0, lb);
    gload_lds16(gbBase + k0 + (size_t)64 * Edim, lb + 64 * BK);
    __syncthreads();  // drains vmcnt before barrier

    f16x8 af[4], bf[4];
#pragma unroll
    for (int i = 0; i < 4; i++)
      af[i] = *(const f16x8*)&As[(wm + i * 16 + row16) * BK + quad * 8];
#pragma unroll
    for (int j = 0; j < 4; j++)
      bf[j] = *(const f16x8*)&Bs[(wn + j * 16 + row16) * BK + quad * 8];
#pragma unroll
    for (int i = 0; i < 4; i++)
#pragma unroll
      for (int j = 0; j < 4; j++)
        acc[i][j] = __builtin_amdgcn_mfma_f32_16x16x32_f16(af[i], bf[j], acc[i][j], 0, 0, 0);
    __syncthreads();
  }

  // Epilogue. C/D layout: col = lane&15, row = quad*4 + reg  [m89-verified]
#pragma unroll
  for (int j = 0; j < 4; j++) {
    const int col = bn + wn + j * 16 + row16;
    const float bv = bias[col];
#pragma unroll
    for (int i = 0; i < 4; i++) {
      const int rb = bm + wm + i * 16 + quad * 4;
#pragma unroll
      for (int r = 0; r < 4; r++)
        C[(size_t)(rb + r) * Edim + col] = (TOut)(acc[i][j][r] + bv);
    }
  }
}

__global__ __launch_bounds__(256) void qkv_kernel(
    const f16_t* __restrict__ x,
    const f16_t* __restrict__ Wq, const float* __restrict__ bq,
    const f16_t* __restrict__ Wk, const float* __restrict__ bk,
    const f16_t* __restrict__ Wv, const float* __restrict__ bv,
    f16_t* __restrict__ Qb, f16_t* __restrict__ Kb, f16_t* __restrict__ Vb) {
  const f16_t* W; const float* bi; f16_t* C;
  if (blockIdx.z == 0)      { W = Wq; bi = bq; C = Qb; }
  else if (blockIdx.z == 1) { W = Wk; bi = bk; C = Kb; }
  else                      { W = Wv; bi = bv; C = Vb; }
  gemm_f16<f16_t>(x, W, bi, C);
}

__global__ __launch_bounds__(256) void outp_kernel(
    const f16_t* __restrict__ Ab, const f16_t* __restrict__ Wo,
    const float* __restrict__ bo, float* __restrict__ out) {
  gemm_f16<float>(Ab, Wo, bo, out);
}

// ---------------- per-position head-attention (one wave / position) ----------
// S^T = K_heads(16x64) @ Q_heads^T via 2x mfma_f32_16x16x32_f16(A=K, B=Q):
//   lane holds S[q = lane&15][k = quad*4+reg]  (q=col, k=row of D)
// softmax over k = 3 in-lane ops + shfl_xor(16), shfl_xor(32).
// P then sits in the A-frag layout of mfma_f32_16x16x16f16 (m=lane&15,
// k=quad*4+j) -> PV with no transpose. V B-frags read from LDS-staged V row.
// Output written to Ab in SCRAMBLED layout:
//   (n,h,s,d) -> row n*4096 + h*256 + s/16, col (s%16)*64 + d
__global__ __launch_bounds__(256) void attn_kernel(const f16_t* __restrict__ Qb,
                                                   const f16_t* __restrict__ Kb,
                                                   const f16_t* __restrict__ Vb,
                                                   f16_t* __restrict__ Ab) {
  __shared__ __align__(16) f16_t Vs[4][1024];  // per-wave V row (2KB each)
  const int t = threadIdx.x;
  const int w = t >> 6;
  const int lane = t & 63;
  const int l16 = lane & 15;
  const int quad = lane >> 4;
  const int pos = blockIdx.x * 4 + w;           // n*S + s
  const int n4 = pos >> 12;
  const int s = pos & (Sdim - 1);

  const f16_t* Qr = Qb + (size_t)pos * Edim;
  const f16_t* Kr = Kb + (size_t)pos * Edim;
  const f16_t* Vr = Vb + (size_t)pos * Edim;

  // stage V row into LDS (coalesced: 32B/lane)
  *(f16x8*)&Vs[w][lane * 16]     = *(const f16x8*)(Vr + lane * 16);
  *(f16x8*)&Vs[w][lane * 16 + 8] = *(const f16x8*)(Vr + lane * 16 + 8);

  // scores: S^T via 2 MFMA steps over head-dim 64
  f32x4 sacc = {};
#pragma unroll
  for (int step = 0; step < 2; step++) {
    const int off = l16 * 64 + step * 32 + quad * 8;
    const f16x8 kf = *(const f16x8*)(Kr + off);  // A: K[m=l16][k]
    const f16x8 qf = *(const f16x8*)(Qr + off);  // B: Q[n=l16][k]
    sacc = __builtin_amdgcn_mfma_f32_16x16x32_f16(kf, qf, sacc, 0, 0, 0);
  }
  // lane holds S[q=l16][kh = quad*4+reg], scaled by 1/sqrt(64)
#pragma unroll
  for (int r = 0; r < 4; r++) sacc[r] *= 0.125f;

  // softmax over kh (in-lane regs + cross-quad shuffles)
  float m = fmaxf(fmaxf(sacc[0], sacc[1]), fmaxf(sacc[2], sacc[3]));
  m = fmaxf(m, __shfl_xor(m, 16));
  m = fmaxf(m, __shfl_xor(m, 32));
  float e[4];
#pragma unroll
  for (int r = 0; r < 4; r++) e[r] = __expf(sacc[r] - m);
  float l = (e[0] + e[1]) + (e[2] + e[3]);
  l += __shfl_xor(l, 16);
  l += __shfl_xor(l, 32);
  const float inv = 1.0f / l;
  f16x4 pa;  // P in A-frag layout: P[q=l16][l=quad*4+j]
#pragma unroll
  for (int r = 0; r < 4; r++) pa[r] = (f16_t)(e[r] * inv);

  // PV: O[q][d] over 4 d-chunks of 16, K-dim = 16 heads
  __syncthreads();  // waves independent, but ensure Vs visible to own wave lanes
  f32x4 oacc[4];
#pragma unroll
  for (int dc = 0; dc < 4; dc++) {
    f16x4 vbf;  // B: V^T[n=d_sub=l16][k=l=quad*4+j] = Vs[l][dc*16+l16]
#pragma unroll
    for (int j = 0; j < 4; j++)
      vbf[j] = Vs[w][(quad * 4 + j) * 64 + dc * 16 + l16];
    f32x4 z = {};
    oacc[dc] = __builtin_amdgcn_mfma_f32_16x16x16f16(pa, vbf, z, 0, 0, 0);
  }

  // scrambled store: lane holds O[q=quad*4+reg][d=dc*16+l16]
  const size_t obase =
      ((size_t)(n4 << 12) + (size_t)(s >> 4)) * Edim + (size_t)(s & 15) * 64 + l16;
#pragma unroll
  for (int reg = 0; reg < 4; reg++) {
    const size_t rowoff = obase + (size_t)(quad * 4 + reg) * 256 * Edim;
#pragma unroll
    for (int dc = 0; dc < 4; dc++)
      Ab[rowoff + dc * 16] = (f16_t)oacc[dc][reg];
  }
}

// ---------------- launcher ----------------
extern "C" void kernel_launch(void* const* d_in, const int* in_sizes, int n_in,
                              void* d_out, int out_size, void* d_ws, size_t ws_size,
                              hipStream_t stream) {
  const float* x  = (const float*)d_in[0];
  const float* Wq = (const float*)d_in[1];
  const float* bq = (const float*)d_in[2];
  const float* Wk = (const float*)d_in[3];
  const float* bk = (const float*)d_in[4];
  const float* Wv = (const float*)d_in[5];
  const float* bv = (const float*)d_in[6];
  const float* Wo = (const float*)d_in[7];
  const float* bo = (const float*)d_in[8];
  float* out = (float*)d_out;

  f16_t* xh  = (f16_t*)d_ws;          // 33.5 MB
  f16_t* Wqh = xh + MATEL;            // 2 MB each
  f16_t* Wkh = Wqh + WEL;
  f16_t* Wvh = Wkh + WEL;
  f16_t* Woh = Wvh + WEL;
  f16_t* Qb  = Woh + WEL;             // 33.5 MB each
  f16_t* Kb  = Qb + MATEL;
  f16_t* Vb  = Kb + MATEL;
  f16_t* Ab  = Vb + MATEL;            // total ~176 MB

  const dim3 blk(256);
  cvt_kernel<<<dim3(2048, 5), blk, 0, stream>>>(x, Wq, Wk, Wv, Wo,
                                                xh, Wqh, Wkh, Wvh, Woh);
  qkv_kernel<<<dim3(Mrows / BM, Edim / BN, 3), blk, 0, stream>>>(
      xh, Wqh, bq, Wkh, bk, Wvh, bv, Qb, Kb, Vb);
  attn_kernel<<<dim3(Mrows / 4), blk, 0, stream>>>(Qb, Kb, Vb, Ab);
  outp_kernel<<<dim3(Mrows / BM, Edim / BN), blk, 0, stream>>>(Ab, Woh, bo, out);
}